// Round 1
// baseline (6998.766 us; speedup 1.0000x reference)
//
#include <hip/hip_runtime.h>
#include <math.h>

// Decoder: B=4, TT=TS=512, D=512, H=8 (each head D->D!), L=2, V=32000.
// Outputs: logits [4,512,32001] fp32, att0 [4,8,512,512] fp32 (layer-0 cross-attn).

#define DV 512
#define NHEAD 8
#define NB 4
#define VOCAB 32000

enum { M_NN = 0, M_PROJ = 1, M_NT = 2, M_AV = 3 };

// 128x128 tile fp32 GEMM, BK=16, 256 threads, 8x8 per-thread register tile.
// MODE_NN:   C[M,N] = A[M,K]@B[K,N] + bias[N] (opt relu). Bounds-guarded in N.
// MODE_PROJ: A[M=B*T, 512] @ W[H,512,512] + bq[H,512] -> out[b,h,t,e] (headed).
// MODE_NT:   batched (z): C[z] = A[z][M,K] @ B[z][N,K]^T * scale.
// MODE_AV:   batched (z=b*H+h): C = A[z][M,K]@B[z][K,N] -> out[b,t, h*512+e].
template<int MODE, int RELU>
__global__ __launch_bounds__(256) void gemm128(
    const float* __restrict__ Ag, const float* __restrict__ Bg,
    const float* __restrict__ bias, float* __restrict__ Cg,
    int M, int N, int K, float scale)
{
  __shared__ float As[16][132];
  __shared__ float Bs[16][132];
  const int tid = threadIdx.x;
  const int n0 = blockIdx.x * 128;
  const int m0 = blockIdx.y * 128;
  const int z  = blockIdx.z;

  const float* A  = Ag;
  const float* Bm = Bg;
  int ldb = N;
  int hHead = 0;
  if constexpr (MODE == M_PROJ) {
    hHead = n0 >> 9;
    Bm = Bg + ((size_t)hHead << 18);   // h*512*512
    ldb = 512;
  } else if constexpr (MODE == M_NT) {
    A  = Ag + (size_t)z * M * K;
    Bm = Bg + (size_t)z * N * K;       // [N,K] row-major
  } else if constexpr (MODE == M_AV) {
    A  = Ag + (size_t)z * M * K;
    Bm = Bg + (size_t)z * K * N;
  }
  const int eoff = (MODE == M_PROJ) ? (n0 & 511) : n0;

  const int ar  = tid >> 1;          // 0..127
  const int ac8 = (tid & 1) << 3;    // 0 or 8
  const int br  = tid >> 4;          // 0..15
  const int bc8 = (tid & 15) << 3;   // 0..120
  const int tx = tid & 15, ty = tid >> 4;

  float acc[8][8] = {};

  for (int k0 = 0; k0 < K; k0 += 16) {
    // A tile (transposed store): As[k][m]
    {
      const float* ap = A + (size_t)(m0 + ar) * K + (k0 + ac8);
      float4 a0 = *(const float4*)ap;
      float4 a1 = *(const float4*)(ap + 4);
      As[ac8 + 0][ar] = a0.x; As[ac8 + 1][ar] = a0.y;
      As[ac8 + 2][ar] = a0.z; As[ac8 + 3][ar] = a0.w;
      As[ac8 + 4][ar] = a1.x; As[ac8 + 5][ar] = a1.y;
      As[ac8 + 6][ar] = a1.z; As[ac8 + 7][ar] = a1.w;
    }
    if constexpr (MODE == M_NT) {
      // B is [N,K]: transpose-load like A: Bs[k][n]
      const float* bp = Bm + (size_t)(n0 + ar) * K + (k0 + ac8);
      float4 b0 = *(const float4*)bp;
      float4 b1 = *(const float4*)(bp + 4);
      Bs[ac8 + 0][ar] = b0.x; Bs[ac8 + 1][ar] = b0.y;
      Bs[ac8 + 2][ar] = b0.z; Bs[ac8 + 3][ar] = b0.w;
      Bs[ac8 + 4][ar] = b1.x; Bs[ac8 + 5][ar] = b1.y;
      Bs[ac8 + 6][ar] = b1.z; Bs[ac8 + 7][ar] = b1.w;
    } else {
      const float* bp = Bm + (size_t)(k0 + br) * ldb + (eoff + bc8);
      const int nb = (MODE == M_PROJ) ? 512 : N;
      if (((ldb & 3) == 0) && (eoff + bc8 + 8 <= nb)) {
        *(float4*)&Bs[br][bc8]     = *(const float4*)bp;
        *(float4*)&Bs[br][bc8 + 4] = *(const float4*)(bp + 4);
      } else {
        #pragma unroll
        for (int i = 0; i < 8; i++) {
          int nn = eoff + bc8 + i;
          Bs[br][bc8 + i] = (nn < nb) ? bp[i] : 0.0f;
        }
      }
    }
    __syncthreads();
    #pragma unroll
    for (int kk = 0; kk < 16; kk++) {
      float a[8], b[8];
      *(float4*)&a[0] = *(const float4*)&As[kk][(ty << 3)];
      *(float4*)&a[4] = *(const float4*)&As[kk][(ty << 3) + 4];
      *(float4*)&b[0] = *(const float4*)&Bs[kk][(tx << 3)];
      *(float4*)&b[4] = *(const float4*)&Bs[kk][(tx << 3) + 4];
      #pragma unroll
      for (int i = 0; i < 8; i++)
        #pragma unroll
        for (int j = 0; j < 8; j++)
          acc[i][j] += a[i] * b[j];
    }
    __syncthreads();
  }

  if constexpr (MODE == M_NN) {
    #pragma unroll
    for (int i = 0; i < 8; i++) {
      int m = m0 + (ty << 3) + i;
      float* crow = Cg + (size_t)m * N + n0 + (tx << 3);
      #pragma unroll
      for (int j = 0; j < 8; j++) {
        int n = n0 + (tx << 3) + j;
        if (n < N) {
          float v = acc[i][j] + bias[n];
          if (RELU) v = fmaxf(v, 0.0f);
          crow[j] = v;
        }
      }
    }
  } else if constexpr (MODE == M_PROJ) {
    const int e0 = (n0 & 511) + (tx << 3);
    #pragma unroll
    for (int i = 0; i < 8; i++) {
      int m = m0 + (ty << 3) + i;
      int bb = m >> 9, tt = m & 511;  // T = 512
      float* crow = Cg + (((size_t)(bb * NHEAD + hHead) << 9) + tt) * DV + e0;
      #pragma unroll
      for (int j = 0; j < 8; j++)
        crow[j] = acc[i][j] + bias[(hHead << 9) + e0 + j];
    }
  } else if constexpr (MODE == M_NT) {
    float* Cz = Cg + (size_t)z * M * N;
    #pragma unroll
    for (int i = 0; i < 8; i++) {
      int m = m0 + (ty << 3) + i;
      float* crow = Cz + (size_t)m * N + n0 + (tx << 3);
      #pragma unroll
      for (int j = 0; j < 8; j++)
        crow[j] = acc[i][j] * scale;
    }
  } else { // M_AV
    int bb = z >> 3, hh = z & 7;
    #pragma unroll
    for (int i = 0; i < 8; i++) {
      int m = m0 + (ty << 3) + i;
      float* crow = Cg + ((size_t)(bb * 512 + m) * 4096) + (hh << 9) + n0 + (tx << 3);
      #pragma unroll
      for (int j = 0; j < 8; j++)
        crow[j] = acc[i][j];
    }
  }
}

__device__ __forceinline__ float waveSum(float v) {
  #pragma unroll
  for (int o = 32; o > 0; o >>= 1) v += __shfl_xor(v, o, 64);
  return v;
}
__device__ __forceinline__ float waveMax(float v) {
  #pragma unroll
  for (int o = 32; o > 0; o >>= 1) v = fmaxf(v, __shfl_xor(v, o, 64));
  return v;
}
__device__ __forceinline__ float blockSum(float v, float* red) {
  v = waveSum(v);
  int w = threadIdx.x >> 6;
  if ((threadIdx.x & 63) == 0) red[w] = v;
  __syncthreads();
  float r = red[0] + red[1] + red[2] + red[3];
  __syncthreads();
  return r;
}
__device__ __forceinline__ float blockMax(float v, float* red) {
  v = waveMax(v);
  int w = threadIdx.x >> 6;
  if ((threadIdx.x & 63) == 0) red[w] = v;
  __syncthreads();
  float r = fmaxf(fmaxf(red[0], red[1]), fmaxf(red[2], red[3]));
  __syncthreads();
  return r;
}

// x[b,t,:] = emb[target[b,t]] + PE(t,:)
__global__ __launch_bounds__(256) void embed_pe(
    const int* __restrict__ target, const float* __restrict__ emb,
    float* __restrict__ x)
{
  int bt = blockIdx.x;          // b*512 + t
  int t = bt & 511;
  int tok = target[bt];
  const float* e = emb + (size_t)tok * DV;
  float* xo = x + ((size_t)bt << 9);
  for (int d = threadIdx.x; d < DV; d += 256) {
    float fi = (float)(d >> 1);
    float denom = powf(10000.0f, fi * (2.0f / 512.0f));
    float zz = (float)t / denom;
    xo[d] = e[d] + ((d & 1) ? cosf(zz) : sinf(zz));
  }
}

// masked softmax over att rows of length 512. CROSS=0: causal+tgt_pad; 1: src_pad+tgt_pad
template<int CROSS>
__global__ __launch_bounds__(256) void softmax_mask(
    float* __restrict__ att, const int* __restrict__ target,
    const int* __restrict__ srcpad)
{
  __shared__ float red[4];
  int r = blockIdx.x;           // z*512 + q, z = b*H + h
  int q = r & 511;
  int z = r >> 9;
  int b = z >> 3;
  float* row = att + ((size_t)r << 9);
  int qv = (target[(b << 9) + q] != VOCAB);
  int t = threadIdx.x;
  int k0 = t, k1 = t + 256;
  int m0, m1;
  if (CROSS) {
    m0 = qv && (srcpad[(b << 9) + k0] != 0);
    m1 = qv && (srcpad[(b << 9) + k1] != 0);
  } else {
    m0 = qv && (target[(b << 9) + k0] != VOCAB) && (k0 <= q);
    m1 = qv && (target[(b << 9) + k1] != VOCAB) && (k1 <= q);
  }
  float v0 = m0 ? row[k0] : -1e32f;
  float v1 = m1 ? row[k1] : -1e32f;
  float mx = blockMax(fmaxf(v0, v1), red);
  float e0 = expf(v0 - mx);
  float e1 = expf(v1 - mx);
  float s = blockSum(e0 + e1, red);
  float inv = 1.0f / s;
  row[k0] = e0 * inv;
  row[k1] = e1 * inv;
}

// x[row] = LayerNorm(x[row] + a[row]) * g + b
__global__ __launch_bounds__(256) void add_ln(
    float* __restrict__ x, const float* __restrict__ a,
    const float* __restrict__ g, const float* __restrict__ bb)
{
  __shared__ float red[4];
  int r = blockIdx.x;
  float* xr = x + ((size_t)r << 9);
  const float* ar = a + ((size_t)r << 9);
  int t = threadIdx.x;
  float v0 = xr[t] + ar[t];
  float v1 = xr[t + 256] + ar[t + 256];
  float mean = blockSum(v0 + v1, red) * (1.0f / 512.0f);
  float d0 = v0 - mean, d1 = v1 - mean;
  float var = blockSum(d0 * d0 + d1 * d1, red) * (1.0f / 512.0f);
  float inv = 1.0f / sqrtf(var + 1e-5f);
  xr[t]       = d0 * inv * g[t] + bb[t];
  xr[t + 256] = d1 * inv * g[t + 256] + bb[t + 256];
}

extern "C" void kernel_launch(void* const* d_in, const int* in_sizes, int n_in,
                              void* d_out, int out_size, void* d_ws, size_t ws_size,
                              hipStream_t stream)
{
  const float* enc    = (const float*)d_in[0];
  const int*   srcpad = (const int*)d_in[1];
  const int*   target = (const int*)d_in[2];
  const float* emb    = (const float*)d_in[3];
  const float* Wq1 = (const float*)d_in[4];
  const float* bq1 = (const float*)d_in[5];
  const float* Wk1 = (const float*)d_in[6];
  const float* bk1 = (const float*)d_in[7];
  const float* Wv1 = (const float*)d_in[8];
  const float* bv1 = (const float*)d_in[9];
  const float* Wo1 = (const float*)d_in[10];
  const float* bo1 = (const float*)d_in[11];
  const float* Wq2 = (const float*)d_in[12];
  const float* bq2 = (const float*)d_in[13];
  const float* Wk2 = (const float*)d_in[14];
  const float* bk2 = (const float*)d_in[15];
  const float* Wv2 = (const float*)d_in[16];
  const float* bv2 = (const float*)d_in[17];
  const float* Wo2 = (const float*)d_in[18];
  const float* bo2 = (const float*)d_in[19];
  const float* ln1g = (const float*)d_in[20];
  const float* ln2g = (const float*)d_in[21];
  const float* ln3g = (const float*)d_in[22];
  const float* ln1b = (const float*)d_in[23];
  const float* ln2b = (const float*)d_in[24];
  const float* ln3b = (const float*)d_in[25];
  const float* Wff1 = (const float*)d_in[26];
  const float* bff1 = (const float*)d_in[27];
  const float* Wff2 = (const float*)d_in[28];
  const float* bff2 = (const float*)d_in[29];
  const float* lmW  = (const float*)d_in[30];
  const float* lmb  = (const float*)d_in[31];

  float* ws = (float*)d_ws;
  float* x    = ws;                  // 1M floats
  float* abuf = x + (1u << 20);      // 1M
  float* qb   = abuf + (1u << 20);   // 8M
  float* kb   = qb + (8u << 20);     // 8M
  float* vb   = kb + (8u << 20);     // 8M
  float* att  = vb + (8u << 20);     // 8M
  float* ao   = qb;                  // reuse: Q dead after scores
  float* ff   = att;                 // reuse: att dead after AV (and att0 copied)

  float* logits = (float*)d_out;                    // 2048*32001
  float* att0   = logits + (size_t)2048 * 32001;    // 4*8*512*512

  const float scale = 0.044194173824159216f;  // 1/sqrt(512)
  dim3 thr(256);

  embed_pe<<<dim3(2048), thr, 0, stream>>>(target, emb, x);

  for (int l = 0; l < 2; l++) {
    size_t wOff  = (size_t)l * NHEAD * DV * DV;  // headed W
    size_t bOff  = (size_t)l * NHEAD * DV;       // headed bias
    size_t woOff = (size_t)l * (NHEAD * DV) * DV;
    size_t dOff  = (size_t)l * DV;

    // ---- self attention ----
    gemm128<M_PROJ,0><<<dim3(32,16,1), thr, 0, stream>>>(x, Wq1+wOff, bq1+bOff, qb, 2048, 4096, 512, 1.f);
    gemm128<M_PROJ,0><<<dim3(32,16,1), thr, 0, stream>>>(x, Wk1+wOff, bk1+bOff, kb, 2048, 4096, 512, 1.f);
    gemm128<M_PROJ,0><<<dim3(32,16,1), thr, 0, stream>>>(x, Wv1+wOff, bv1+bOff, vb, 2048, 4096, 512, 1.f);
    gemm128<M_NT,0><<<dim3(4,4,32), thr, 0, stream>>>(qb, kb, nullptr, att, 512, 512, 512, scale);
    softmax_mask<0><<<dim3(16384), thr, 0, stream>>>(att, target, srcpad);
    gemm128<M_AV,0><<<dim3(4,4,32), thr, 0, stream>>>(att, vb, nullptr, ao, 512, 512, 512, 1.f);
    gemm128<M_NN,0><<<dim3(4,16,1), thr, 0, stream>>>(ao, Wo1+woOff, bo1+dOff, abuf, 2048, 512, 4096, 1.f);
    add_ln<<<dim3(2048), thr, 0, stream>>>(x, abuf, ln1g+dOff, ln1b+dOff);

    // ---- cross attention ----
    gemm128<M_PROJ,0><<<dim3(32,16,1), thr, 0, stream>>>(x,   Wq2+wOff, bq2+bOff, qb, 2048, 4096, 512, 1.f);
    gemm128<M_PROJ,0><<<dim3(32,16,1), thr, 0, stream>>>(enc, Wk2+wOff, bk2+bOff, kb, 2048, 4096, 512, 1.f);
    gemm128<M_PROJ,0><<<dim3(32,16,1), thr, 0, stream>>>(enc, Wv2+wOff, bv2+bOff, vb, 2048, 4096, 512, 1.f);
    gemm128<M_NT,0><<<dim3(4,4,32), thr, 0, stream>>>(qb, kb, nullptr, att, 512, 512, 512, scale);
    softmax_mask<1><<<dim3(16384), thr, 0, stream>>>(att, target, srcpad);
    if (l == 0)
      hipMemcpyAsync(att0, att, sizeof(float) * (size_t)8388608,
                     hipMemcpyDeviceToDevice, stream);
    gemm128<M_AV,0><<<dim3(4,4,32), thr, 0, stream>>>(att, vb, nullptr, ao, 512, 512, 512, 1.f);
    gemm128<M_NN,0><<<dim3(4,16,1), thr, 0, stream>>>(ao, Wo2+woOff, bo2+dOff, abuf, 2048, 512, 4096, 1.f);
    add_ln<<<dim3(2048), thr, 0, stream>>>(x, abuf, ln2g+dOff, ln2b+dOff);

    // ---- feed-forward ----
    gemm128<M_NN,1><<<dim3(16,16,1), thr, 0, stream>>>(x, Wff1 + (size_t)l*512*2048, bff1 + (size_t)l*2048, ff, 2048, 2048, 512, 1.f);
    gemm128<M_NN,0><<<dim3(4,16,1), thr, 0, stream>>>(ff, Wff2 + (size_t)l*2048*512, bff2+dOff, abuf, 2048, 512, 2048, 1.f);
    add_ln<<<dim3(2048), thr, 0, stream>>>(x, abuf, ln3g+dOff, ln3b+dOff);
  }

  // LM head: [2048,512] @ [512,32001] + lm_b
  gemm128<M_NN,0><<<dim3(251,16,1), thr, 0, stream>>>(x, lmW, lmb, logits, 2048, 32001, 512, 1.f);
}

// Round 4
// 1774.832 us; speedup vs baseline: 3.9433x; 3.9433x over previous
//
#include <hip/hip_runtime.h>
#include <hip/hip_bf16.h>
#include <math.h>

// Decoder: B=4, TT=TS=512, D=512, H=8 (each head D->D), L=2, V=32000.
// Outputs: logits [4,512,32001] fp32, att0 [4,8,512,512] fp32.
// All GEMMs: bf16 MFMA (16x16x32), fp32 accumulate. Softmax/LN/residual fp32.
// Workspace budget: 128.6 MB (proven-safe bound from round 1: 136 MB).

#define DV 512
#define NHEAD 8
#define VOCAB 32000

typedef __attribute__((ext_vector_type(8))) short short8;
typedef __attribute__((ext_vector_type(4))) float f32x4;

__device__ __forceinline__ void gld16(const void* g, const void* l) {
  __builtin_amdgcn_global_load_lds(
      (const __attribute__((address_space(1))) unsigned int*)g,
      (__attribute__((address_space(3))) unsigned int*)l, 16, 0, 0);
}

// ---------------- MFMA GEMM: C = A[M,K] @ B[N,K]^T ----------------
// 128x128 tile, BK=32, 256 thr (4 waves, 2x2), each wave 64x64 = 4x4 frags.
// LDS: fragment-ordered subtiles (16 rows x 32 k), staged via global_load_lds.
enum { MM_NN = 0, MM_NN_B16 = 1, MM_QK = 2, MM_VT = 3, MM_SC = 4, MM_AV = 5 };

template<int MODE, int RELU>
__global__ __launch_bounds__(256) void mgemm(
    const __hip_bfloat16* __restrict__ Ag,
    const __hip_bfloat16* __restrict__ Bg,
    const float* __restrict__ bias,
    float* __restrict__ Cf, __hip_bfloat16* __restrict__ Cb,
    int M, int N, int K, float scale)
{
  __shared__ __hip_bfloat16 sm[2][2][4096];   // [buf][A/B][8 subtiles * 512]
  const int tid  = threadIdx.x;
  const int lane = tid & 63;
  const int wid  = tid >> 6;
  const int wr = wid >> 1, wc = wid & 1;
  const int n0 = blockIdx.x * 128;
  const int m0 = blockIdx.y * 128;
  const int z  = blockIdx.z;

  const __hip_bfloat16* A = Ag;
  const __hip_bfloat16* B = Bg;
  int h = 0;
  if constexpr (MODE == MM_QK || MODE == MM_VT) {
    h = n0 >> 9;
    B = Bg + ((size_t)h << 18);      // per-head [512][512]
  } else if constexpr (MODE == MM_SC || MODE == MM_AV) {
    A = Ag + ((size_t)z << 18);
    B = Bg + ((size_t)z << 18);
  }
  const int nb0 = (MODE == MM_QK || MODE == MM_VT) ? (n0 & 511) : n0;

  const int lr = lane & 15;          // row within 16-row subtile
  const int lk = (lane >> 4) << 3;   // k offset 0/8/16/24
  const int s0 = wid * 2;            // this wave stages subtiles s0, s0+1 (A and B)

  const char* aS0 = (const char*)(A + (size_t)(m0 + s0 * 16 + lr) * K) + lk * 2;
  const char* aS1 = aS0 + (size_t)16 * K * 2;
  const char* bS0 = (const char*)(B + (size_t)(nb0 + s0 * 16 + lr) * K) + lk * 2;
  const char* bS1 = bS0 + (size_t)16 * K * 2;

  f32x4 acc[4][4] = {};

  const int nt = K >> 5;             // K / 32
  // prologue stage
  {
    gld16(aS0, &sm[0][0][(s0) * 512]);
    gld16(aS1, &sm[0][0][(s0 + 1) * 512]);
    gld16(bS0, &sm[0][1][(s0) * 512]);
    gld16(bS1, &sm[0][1][(s0 + 1) * 512]);
  }
  __syncthreads();
  int cur = 0;
  for (int t = 0; t < nt; ++t) {
    if (t + 1 < nt) {
      size_t ko = (size_t)(t + 1) * 64;   // 32 bf16 = 64 bytes per K-step
      int nb = cur ^ 1;
      gld16(aS0 + ko, &sm[nb][0][(s0) * 512]);
      gld16(aS1 + ko, &sm[nb][0][(s0 + 1) * 512]);
      gld16(bS0 + ko, &sm[nb][1][(s0) * 512]);
      gld16(bS1 + ko, &sm[nb][1][(s0 + 1) * 512]);
    }
    short8 af[4], bf[4];
    #pragma unroll
    for (int i = 0; i < 4; i++)
      af[i] = *(const short8*)(&sm[cur][0][(wr * 4 + i) * 512 + lane * 8]);
    #pragma unroll
    for (int j = 0; j < 4; j++)
      bf[j] = *(const short8*)(&sm[cur][1][(wc * 4 + j) * 512 + lane * 8]);
    #pragma unroll
    for (int i = 0; i < 4; i++)
      #pragma unroll
      for (int j = 0; j < 4; j++)
        acc[i][j] = __builtin_amdgcn_mfma_f32_16x16x32_bf16(af[i], bf[j], acc[i][j], 0, 0, 0);
    __syncthreads();   // drains vmcnt+lgkm: next buffer staged, this buffer free
    cur ^= 1;
  }

  // epilogue: frag (i,j): row = m0+wr*64+i*16+(lane>>4)*4+r, col = n0+wc*64+j*16+(lane&15)
  const int rb = m0 + wr * 64 + ((lane >> 4) << 2);
  const int cb = n0 + wc * 64 + (lane & 15);
  #pragma unroll
  for (int i = 0; i < 4; i++) {
    #pragma unroll
    for (int j = 0; j < 4; j++) {
      f32x4 v = acc[i][j];
      const int col = cb + j * 16;
      if constexpr (MODE == MM_NN) {
        if (col < N) {
          float bb = bias[col];
          #pragma unroll
          for (int r = 0; r < 4; r++) {
            float o = v[r] + bb;
            if (RELU) o = fmaxf(o, 0.0f);
            Cf[(size_t)(rb + i * 16 + r) * N + col] = o;
          }
        }
      } else if constexpr (MODE == MM_NN_B16) {
        float bb = bias[col];
        #pragma unroll
        for (int r = 0; r < 4; r++) {
          float o = v[r] + bb;
          if (RELU) o = fmaxf(o, 0.0f);
          Cb[(size_t)(rb + i * 16 + r) * N + col] = __float2bfloat16(o);
        }
      } else if constexpr (MODE == MM_QK) {
        float bb = bias[col];
        const int e = col & 511;
        #pragma unroll
        for (int r = 0; r < 4; r++) {
          int m = rb + i * 16 + r;
          size_t idx = ((size_t)((m >> 9) * NHEAD + h) * 512 + (m & 511)) * 512 + e;
          Cb[idx] = __float2bfloat16(v[r] + bb);
        }
      } else if constexpr (MODE == MM_VT) {
        float bb = bias[col];
        const int e = col & 511;
        #pragma unroll
        for (int r = 0; r < 4; r++) {
          int m = rb + i * 16 + r;
          size_t idx = ((size_t)((m >> 9) * NHEAD + h) * 512 + e) * 512 + (m & 511);
          Cb[idx] = __float2bfloat16(v[r] + bb);
        }
      } else if constexpr (MODE == MM_SC) {
        #pragma unroll
        for (int r = 0; r < 4; r++)
          Cf[((size_t)z << 18) + (size_t)(rb + i * 16 + r) * 512 + col] = v[r] * scale;
      } else { // MM_AV
        const int bb_ = z >> 3, hh = z & 7;
        #pragma unroll
        for (int r = 0; r < 4; r++) {
          int m = rb + i * 16 + r;
          Cb[((size_t)(bb_ * 512 + m) * 4096) + (hh << 9) + col] = __float2bfloat16(v[r]);
        }
      }
    }
  }
}

// ---------------- weight fp32 -> bf16 transposed conversion ----------------
// job: src fp32 [Z][R][C] -> dst bf16 [Z][Cp][R]; pads c in [C,Cp) with 0.
struct TJob { const float* src; __hip_bfloat16* dst; int Z, R, C, Cp; };
struct TJobs { TJob j[6]; int off[7]; int n; };

__global__ __launch_bounds__(256) void transpose_jobs(TJobs J) {
  __shared__ float lds[32][33];
  int t = blockIdx.x;
  int ji = 0;
  while (ji + 1 < J.n && t >= J.off[ji + 1]) ji++;
  const TJob& job = J.j[ji];
  int loc = t - J.off[ji];
  int rT = job.R >> 5, cT = job.Cp >> 5;
  int tpz = rT * cT;
  int z = loc / tpz, rem = loc - z * tpz;
  int ct = rem / rT, rt = rem - ct * rT;

  const float* s = job.src + (size_t)z * job.R * job.C;
  int tid = threadIdx.x;
  {
    int rr = tid >> 3, c4 = (tid & 7) << 2;
    int r = rt * 32 + rr;
    #pragma unroll
    for (int i = 0; i < 4; i++) {
      int c = ct * 32 + c4 + i;
      lds[rr][c4 + i] = (c < job.C) ? s[(size_t)r * job.C + c] : 0.0f;
    }
  }
  __syncthreads();
  {
    int cc = tid >> 3, r4 = (tid & 7) << 2;
    int dRow = ct * 32 + cc;
    __hip_bfloat16* d = job.dst + ((size_t)z * job.Cp + dRow) * job.R + rt * 32 + r4;
    unsigned short out[4];
    #pragma unroll
    for (int i = 0; i < 4; i++) {
      __hip_bfloat16 bv = __float2bfloat16(lds[r4 + i][cc]);
      out[i] = *(unsigned short*)&bv;
    }
    *(ushort4*)d = make_ushort4(out[0], out[1], out[2], out[3]);
  }
}

// ---------------- elementwise ----------------
__device__ __forceinline__ float waveSum(float v) {
  #pragma unroll
  for (int o = 32; o > 0; o >>= 1) v += __shfl_xor(v, o, 64);
  return v;
}
__device__ __forceinline__ float waveMax(float v) {
  #pragma unroll
  for (int o = 32; o > 0; o >>= 1) v = fmaxf(v, __shfl_xor(v, o, 64));
  return v;
}
__device__ __forceinline__ float blockSum(float v, float* red) {
  v = waveSum(v);
  int w = threadIdx.x >> 6;
  if ((threadIdx.x & 63) == 0) red[w] = v;
  __syncthreads();
  float r = red[0] + red[1] + red[2] + red[3];
  __syncthreads();
  return r;
}
__device__ __forceinline__ float blockMax(float v, float* red) {
  v = waveMax(v);
  int w = threadIdx.x >> 6;
  if ((threadIdx.x & 63) == 0) red[w] = v;
  __syncthreads();
  float r = fmaxf(fmaxf(red[0], red[1]), fmaxf(red[2], red[3]));
  __syncthreads();
  return r;
}

__global__ __launch_bounds__(256) void embed_pe(
    const int* __restrict__ target, const float* __restrict__ emb,
    float* __restrict__ x, __hip_bfloat16* __restrict__ xb)
{
  int bt = blockIdx.x;
  int t = bt & 511;
  int tok = target[bt];
  const float* e = emb + (size_t)tok * DV;
  float* xo = x + ((size_t)bt << 9);
  __hip_bfloat16* xbo = xb + ((size_t)bt << 9);
  for (int d = threadIdx.x; d < DV; d += 256) {
    float fi = (float)(d >> 1);
    float denom = powf(10000.0f, fi * (2.0f / 512.0f));
    float zz = (float)t / denom;
    float v = e[d] + ((d & 1) ? cosf(zz) : sinf(zz));
    xo[d] = v;
    xbo[d] = __float2bfloat16(v);
  }
}

__global__ __launch_bounds__(256) void cast_bf16(
    const float* __restrict__ in, __hip_bfloat16* __restrict__ out, int n4)
{
  int i = blockIdx.x * 256 + threadIdx.x;
  if (i < n4) {
    float4 v = *(const float4*)(in + (size_t)i * 4);
    __hip_bfloat16* o = out + (size_t)i * 4;
    o[0] = __float2bfloat16(v.x); o[1] = __float2bfloat16(v.y);
    o[2] = __float2bfloat16(v.z); o[3] = __float2bfloat16(v.w);
  }
}

// masked softmax over rows of length 512; writes bf16 always, fp32 if f32out != null
template<int CROSS>
__global__ __launch_bounds__(256) void softmax_mask(
    const float* __restrict__ att, __hip_bfloat16* __restrict__ attb,
    float* __restrict__ f32out,
    const int* __restrict__ target, const int* __restrict__ srcpad)
{
  __shared__ float red[4];
  int r = blockIdx.x;           // z*512 + q, z = b*H + h
  int q = r & 511;
  int z = r >> 9;
  int b = z >> 3;
  const float* row = att + ((size_t)r << 9);
  int qv = (target[(b << 9) + q] != VOCAB);
  int t = threadIdx.x;
  int k0 = t, k1 = t + 256;
  int m0, m1;
  if (CROSS) {
    m0 = qv && (srcpad[(b << 9) + k0] != 0);
    m1 = qv && (srcpad[(b << 9) + k1] != 0);
  } else {
    m0 = qv && (target[(b << 9) + k0] != VOCAB) && (k0 <= q);
    m1 = qv && (target[(b << 9) + k1] != VOCAB) && (k1 <= q);
  }
  float v0 = m0 ? row[k0] : -1e32f;
  float v1 = m1 ? row[k1] : -1e32f;
  float mx = blockMax(fmaxf(v0, v1), red);
  float e0 = expf(v0 - mx);
  float e1 = expf(v1 - mx);
  float s = blockSum(e0 + e1, red);
  float inv = 1.0f / s;
  e0 *= inv; e1 *= inv;
  __hip_bfloat16* brow = attb + ((size_t)r << 9);
  brow[k0] = __float2bfloat16(e0);
  brow[k1] = __float2bfloat16(e1);
  if (f32out) {
    float* frow = f32out + ((size_t)r << 9);
    frow[k0] = e0; frow[k1] = e1;
  }
}

__global__ __launch_bounds__(256) void add_ln(
    float* __restrict__ x, __hip_bfloat16* __restrict__ xb,
    const float* __restrict__ a,
    const float* __restrict__ g, const float* __restrict__ bb)
{
  __shared__ float red[4];
  int r = blockIdx.x;
  float* xr = x + ((size_t)r << 9);
  __hip_bfloat16* xbr = xb + ((size_t)r << 9);
  const float* ar = a + ((size_t)r << 9);
  int t = threadIdx.x;
  float v0 = xr[t] + ar[t];
  float v1 = xr[t + 256] + ar[t + 256];
  float mean = blockSum(v0 + v1, red) * (1.0f / 512.0f);
  float d0 = v0 - mean, d1 = v1 - mean;
  float var = blockSum(d0 * d0 + d1 * d1, red) * (1.0f / 512.0f);
  float inv = 1.0f / sqrtf(var + 1e-5f);
  float o0 = d0 * inv * g[t] + bb[t];
  float o1 = d1 * inv * g[t + 256] + bb[t + 256];
  xr[t] = o0;       xbr[t] = __float2bfloat16(o0);
  xr[t + 256] = o1; xbr[t + 256] = __float2bfloat16(o1);
}

// ---------------- host ----------------
extern "C" void kernel_launch(void* const* d_in, const int* in_sizes, int n_in,
                              void* d_out, int out_size, void* d_ws, size_t ws_size,
                              hipStream_t stream)
{
  const float* enc    = (const float*)d_in[0];
  const int*   srcpad = (const int*)d_in[1];
  const int*   target = (const int*)d_in[2];
  const float* emb    = (const float*)d_in[3];
  const float* Wq1 = (const float*)d_in[4];
  const float* bq1 = (const float*)d_in[5];
  const float* Wk1 = (const float*)d_in[6];
  const float* bk1 = (const float*)d_in[7];
  const float* Wv1 = (const float*)d_in[8];
  const float* bv1 = (const float*)d_in[9];
  const float* Wo1 = (const float*)d_in[10];
  const float* bo1 = (const float*)d_in[11];
  const float* Wq2 = (const float*)d_in[12];
  const float* bq2 = (const float*)d_in[13];
  const float* Wk2 = (const float*)d_in[14];
  const float* bk2 = (const float*)d_in[15];
  const float* Wv2 = (const float*)d_in[16];
  const float* bv2 = (const float*)d_in[17];
  const float* Wo2 = (const float*)d_in[18];
  const float* bo2 = (const float*)d_in[19];
  const float* ln1g = (const float*)d_in[20];
  const float* ln2g = (const float*)d_in[21];
  const float* ln3g = (const float*)d_in[22];
  const float* ln1b = (const float*)d_in[23];
  const float* ln2b = (const float*)d_in[24];
  const float* ln3b = (const float*)d_in[25];
  const float* Wff1 = (const float*)d_in[26];
  const float* bff1 = (const float*)d_in[27];
  const float* Wff2 = (const float*)d_in[28];
  const float* bff2 = (const float*)d_in[29];
  const float* lmW  = (const float*)d_in[30];
  const float* lmb  = (const float*)d_in[31];

  char* p = (char*)d_ws;
  auto carve = [&](size_t bytes) { char* r = p; p += (bytes + 255) & ~(size_t)255; return r; };
  float*          x     = (float*)carve((size_t)2048 * 512 * 4);            //  4 MB
  __hip_bfloat16* xb    = (__hip_bfloat16*)carve((size_t)2048 * 512 * 2);   //  2 MB
  float*          abuf  = (float*)carve((size_t)2048 * 512 * 4);            //  4 MB
  __hip_bfloat16* encb  = (__hip_bfloat16*)carve((size_t)2048 * 512 * 2);   //  2 MB
  __hip_bfloat16* qb    = (__hip_bfloat16*)carve((size_t)32 * 512 * 512 * 2); // 16 MB
  __hip_bfloat16* kb    = (__hip_bfloat16*)carve((size_t)32 * 512 * 512 * 2); // 16 MB
  __hip_bfloat16* vT    = (__hip_bfloat16*)carve((size_t)32 * 512 * 512 * 2); // 16 MB
  __hip_bfloat16* attb  = (__hip_bfloat16*)carve((size_t)32 * 512 * 512 * 2); // 16 MB
  float*          att   = (float*)carve((size_t)32 * 512 * 512 * 4);        // 32 MB
  __hip_bfloat16* WTqkv = (__hip_bfloat16*)carve((size_t)3 * 8 * 512 * 512 * 2); // 12.6 MB
  __hip_bfloat16* WTo   = (__hip_bfloat16*)carve((size_t)512 * 4096 * 2);   //  4 MB
  __hip_bfloat16* WTff1 = (__hip_bfloat16*)carve((size_t)2048 * 512 * 2);   //  2 MB
  __hip_bfloat16* WTff2 = (__hip_bfloat16*)carve((size_t)512 * 2048 * 2);   //  2 MB
  // total carved: ~128.6 MB (<= 136 MB proven-safe from round 1)
  __hip_bfloat16* ao = qb;                    // Q dead after scores
  __hip_bfloat16* ff = (__hip_bfloat16*)att;  // att fp32 dead after softmax
  __hip_bfloat16* WTlm = qb;                  // qb..vT (48 MB) dead before LM head; need 32.9 MB

  float* logits = (float*)d_out;                    // 2048*32001
  float* att0   = logits + (size_t)2048 * 32001;    // 4*8*512*512

  const float scale = 0.044194173824159216f;  // 1/sqrt(512)
  dim3 thr(256);
  const size_t hWsz = (size_t)8 * 512 * 512;  // per q/k/v weight block (one layer)

  // prep: enc->bf16, embed+PE
  cast_bf16<<<dim3(1024), thr, 0, stream>>>(enc, encb, 262144);
  embed_pe<<<dim3(2048), thr, 0, stream>>>(target, emb, x, xb);

  for (int l = 0; l < 2; l++) {
    size_t wOff  = (size_t)l * hWsz;
    size_t bOff  = (size_t)l * NHEAD * DV;
    size_t woOff = (size_t)l * 4096 * 512;
    size_t dOff  = (size_t)l * DV;

    // ---- convert self-attn weights ----
    {
      TJobs J = {};
      J.n = 4;
      J.j[0] = { Wq1 + wOff, WTqkv,            8, 512, 512, 512 };
      J.j[1] = { Wk1 + wOff, WTqkv + hWsz,     8, 512, 512, 512 };
      J.j[2] = { Wv1 + wOff, WTqkv + 2 * hWsz, 8, 512, 512, 512 };
      J.j[3] = { Wo1 + woOff, WTo,             1, 4096, 512, 512 };
      int c = 0;
      J.off[0] = 0;
      for (int k = 0; k < 4; k++) { c += J.j[k].Z * (J.j[k].R >> 5) * (J.j[k].Cp >> 5); J.off[k + 1] = c; }
      transpose_jobs<<<dim3(c), thr, 0, stream>>>(J);
    }
    // ---- self attention ----
    mgemm<MM_QK, 0><<<dim3(32, 16, 1), thr, 0, stream>>>(xb, WTqkv,            bq1 + bOff, nullptr, qb, 2048, 4096, 512, 1.f);
    mgemm<MM_QK, 0><<<dim3(32, 16, 1), thr, 0, stream>>>(xb, WTqkv + hWsz,     bk1 + bOff, nullptr, kb, 2048, 4096, 512, 1.f);
    mgemm<MM_VT, 0><<<dim3(32, 16, 1), thr, 0, stream>>>(xb, WTqkv + 2 * hWsz, bv1 + bOff, nullptr, vT, 2048, 4096, 512, 1.f);
    mgemm<MM_SC, 0><<<dim3(4, 4, 32), thr, 0, stream>>>(qb, kb, nullptr, att, nullptr, 512, 512, 512, scale);
    softmax_mask<0><<<dim3(16384), thr, 0, stream>>>(att, attb, nullptr, target, srcpad);
    mgemm<MM_AV, 0><<<dim3(4, 4, 32), thr, 0, stream>>>(attb, vT, nullptr, nullptr, ao, 512, 512, 512, 1.f);
    mgemm<MM_NN, 0><<<dim3(4, 16, 1), thr, 0, stream>>>(ao, WTo, bo1 + dOff, abuf, nullptr, 2048, 512, 4096, 1.f);
    add_ln<<<dim3(2048), thr, 0, stream>>>(x, xb, abuf, ln1g + dOff, ln1b + dOff);

    // ---- convert cross-attn + FF weights ----
    {
      TJobs J = {};
      J.n = 6;
      J.j[0] = { Wq2 + wOff, WTqkv,            8, 512, 512, 512 };
      J.j[1] = { Wk2 + wOff, WTqkv + hWsz,     8, 512, 512, 512 };
      J.j[2] = { Wv2 + wOff, WTqkv + 2 * hWsz, 8, 512, 512, 512 };
      J.j[3] = { Wo2 + woOff, WTo,             1, 4096, 512, 512 };
      J.j[4] = { Wff1 + (size_t)l * 512 * 2048, WTff1, 1, 512, 2048, 2048 };
      J.j[5] = { Wff2 + (size_t)l * 2048 * 512, WTff2, 1, 2048, 512, 512 };
      int c = 0;
      J.off[0] = 0;
      for (int k = 0; k < 6; k++) { c += J.j[k].Z * (J.j[k].R >> 5) * (J.j[k].Cp >> 5); J.off[k + 1] = c; }
      transpose_jobs<<<dim3(c), thr, 0, stream>>>(J);
    }
    // ---- cross attention ----
    mgemm<MM_QK, 0><<<dim3(32, 16, 1), thr, 0, stream>>>(xb,   WTqkv,            bq2 + bOff, nullptr, qb, 2048, 4096, 512, 1.f);
    mgemm<MM_QK, 0><<<dim3(32, 16, 1), thr, 0, stream>>>(encb, WTqkv + hWsz,     bk2 + bOff, nullptr, kb, 2048, 4096, 512, 1.f);
    mgemm<MM_VT, 0><<<dim3(32, 16, 1), thr, 0, stream>>>(encb, WTqkv + 2 * hWsz, bv2 + bOff, nullptr, vT, 2048, 4096, 512, 1.f);
    mgemm<MM_SC, 0><<<dim3(4, 4, 32), thr, 0, stream>>>(qb, kb, nullptr, att, nullptr, 512, 512, 512, scale);
    softmax_mask<1><<<dim3(16384), thr, 0, stream>>>(att, attb, (l == 0) ? att0 : nullptr, target, srcpad);
    mgemm<MM_AV, 0><<<dim3(4, 4, 32), thr, 0, stream>>>(attb, vT, nullptr, nullptr, ao, 512, 512, 512, 1.f);
    mgemm<MM_NN, 0><<<dim3(4, 16, 1), thr, 0, stream>>>(ao, WTo, bo2 + dOff, abuf, nullptr, 2048, 512, 4096, 1.f);
    add_ln<<<dim3(2048), thr, 0, stream>>>(x, xb, abuf, ln2g + dOff, ln2b + dOff);

    // ---- feed-forward ----
    mgemm<MM_NN_B16, 1><<<dim3(16, 16, 1), thr, 0, stream>>>(xb, WTff1, bff1 + (size_t)l * 2048, nullptr, ff, 2048, 2048, 512, 1.f);
    mgemm<MM_NN, 0><<<dim3(4, 16, 1), thr, 0, stream>>>(ff, WTff2, bff2 + dOff, abuf, nullptr, 2048, 512, 2048, 1.f);
    add_ln<<<dim3(2048), thr, 0, stream>>>(x, xb, abuf, ln3g + dOff, ln3b + dOff);
  }

  // LM head: transpose lm_W now (qb/kb/vT dead -> 48 MB region holds WTlm 32.9 MB)
  {
    TJobs J = {};
    J.n = 1;
    J.j[0] = { lmW, WTlm, 1, 512, 32001, 32128 };
    J.off[0] = 0; J.off[1] = 16 * 1004;
    transpose_jobs<<<dim3(J.off[1]), thr, 0, stream>>>(J);
  }
  // xb[2048,512] @ WTlm[32128,512]^T + lmb, guarded at N=32001
  mgemm<MM_NN, 0><<<dim3(251, 16, 1), thr, 0, stream>>>(xb, WTlm, lmb, logits, nullptr, 2048, 32001, 512, 1.f);
}